// Round 1
// baseline (26.906 us; speedup 1.0000x reference)
//
#include <hip/hip_runtime.h>
#include <math.h>

#define BATCH 128
#define GRID_N 10000
#define DIM 32
#define MCOLS 100

// ---------------------------------------------------------------------------
// K1: partial BMU search. 64 b-groups (2 rows of x each) x 4 g-chunks (2500)
// = 256 blocks, 256 threads. Direct-diff ||x-c||^2 (accurate), first-index
// tie-break everywhere to match jnp.argmin semantics.
// ---------------------------------------------------------------------------
__global__ __launch_bounds__(256) void k1_bmu(const float* __restrict__ x,
                                              const float* __restrict__ c,
                                              float* __restrict__ pmin,
                                              int* __restrict__ pidx) {
    const int blk   = blockIdx.x;
    const int bg    = blk >> 2;      // 0..63
    const int chunk = blk & 3;       // 0..3
    const int b0    = bg * 2;
    const int t     = threadIdx.x;

    // two x rows; uniform addresses -> compiler can scalarize
    float x0[DIM], x1[DIM];
#pragma unroll
    for (int d = 0; d < DIM; ++d) {
        x0[d] = x[b0 * DIM + d];
        x1[d] = x[(b0 + 1) * DIM + d];
    }

    const int gstart = chunk * 2500;
    const int gend   = gstart + 2500;

    float best0 = 3.4e38f, best1 = 3.4e38f;
    int   idx0 = 0, idx1 = 0;

    for (int g = gstart + t; g < gend; g += 256) {
        const float4* cr = (const float4*)(c + (size_t)g * DIM);
        float d0 = 0.f, d1 = 0.f;
#pragma unroll
        for (int k = 0; k < 8; ++k) {
            float4 cv = cr[k];
            float a;
            a = x0[4*k+0] - cv.x; d0 = fmaf(a, a, d0);
            a = x0[4*k+1] - cv.y; d0 = fmaf(a, a, d0);
            a = x0[4*k+2] - cv.z; d0 = fmaf(a, a, d0);
            a = x0[4*k+3] - cv.w; d0 = fmaf(a, a, d0);
            a = x1[4*k+0] - cv.x; d1 = fmaf(a, a, d1);
            a = x1[4*k+1] - cv.y; d1 = fmaf(a, a, d1);
            a = x1[4*k+2] - cv.z; d1 = fmaf(a, a, d1);
            a = x1[4*k+3] - cv.w; d1 = fmaf(a, a, d1);
        }
        if (d0 < best0) { best0 = d0; idx0 = g; }   // strict <: keeps first
        if (d1 < best1) { best1 = d1; idx1 = g; }
    }

    // wave (64-lane) butterfly reduce, min with smallest-index tie-break
#pragma unroll
    for (int m = 1; m < 64; m <<= 1) {
        float o0 = __shfl_xor(best0, m); int oi0 = __shfl_xor(idx0, m);
        if (o0 < best0 || (o0 == best0 && oi0 < idx0)) { best0 = o0; idx0 = oi0; }
        float o1 = __shfl_xor(best1, m); int oi1 = __shfl_xor(idx1, m);
        if (o1 < best1 || (o1 == best1 && oi1 < idx1)) { best1 = o1; idx1 = oi1; }
    }

    __shared__ float sm[2][4];
    __shared__ int   si[2][4];
    const int wave = t >> 6;
    const int lane = t & 63;
    if (lane == 0) {
        sm[0][wave] = best0; si[0][wave] = idx0;
        sm[1][wave] = best1; si[1][wave] = idx1;
    }
    __syncthreads();
    if (t == 0) {
        float bb = sm[0][0]; int bi = si[0][0];
        for (int w = 1; w < 4; ++w)
            if (sm[0][w] < bb || (sm[0][w] == bb && si[0][w] < bi)) { bb = sm[0][w]; bi = si[0][w]; }
        pmin[b0 * 4 + chunk] = bb;
        pidx[b0 * 4 + chunk] = bi;
        bb = sm[1][0]; bi = si[1][0];
        for (int w = 1; w < 4; ++w)
            if (sm[1][w] < bb || (sm[1][w] == bb && si[1][w] < bi)) { bb = sm[1][w]; bi = si[1][w]; }
        pmin[(b0 + 1) * 4 + chunk] = bb;
        pidx[(b0 + 1) * 4 + chunk] = bi;
    }
}

// ---------------------------------------------------------------------------
// K2: finalize per-b argmin over 4 chunks; write bmu_loc (as float) and
// mean(sqrt(mind2)); stash bmu indices in workspace for K3.
// ---------------------------------------------------------------------------
__global__ __launch_bounds__(128) void k2_final(const float* __restrict__ pmin,
                                                const int* __restrict__ pidx,
                                                const int* __restrict__ loc,
                                                float* __restrict__ out,
                                                int* __restrict__ bmuidx) {
    const int b = threadIdx.x;   // 0..127
    float best = pmin[b * 4];
    int   bi   = pidx[b * 4];
    for (int k = 1; k < 4; ++k) {
        float v = pmin[b * 4 + k];
        int   i = pidx[b * 4 + k];
        if (v < best || (v == best && i < bi)) { best = v; bi = i; }
    }
    out[2 * b]     = (float)loc[2 * bi];
    out[2 * b + 1] = (float)loc[2 * bi + 1];
    bmuidx[b] = bi;

    __shared__ float red[128];
    red[b] = sqrtf(fmaxf(best, 0.f));
    __syncthreads();
    for (int off = 64; off > 0; off >>= 1) {
        if (b < off) red[b] += red[b + off];
        __syncthreads();
    }
    if (b == 0) out[256] = red[0] * (1.0f / 128.0f);
}

// ---------------------------------------------------------------------------
// K3: new_weights. 157 blocks x 256 threads; thread = (g_local = t&63,
// b-chunk = t>>6 of 32 rows). Neighbourhood distance computed from integer
// grid coords (exactly equals distance_mat gather). Register acc[32],
// LDS reduce across the 4 b-chunks, guarded tail write.
// ---------------------------------------------------------------------------
__global__ __launch_bounds__(256) void k3_update(const float* __restrict__ x,
                                                 const float* __restrict__ c,
                                                 const int* __restrict__ loc,
                                                 const int* __restrict__ bmuidx,
                                                 const float* __restrict__ lrp,
                                                 float* __restrict__ out) {
    __shared__ float bi_s[BATCH], bj_s[BATCH];
    __shared__ float red[4][64][33];

    const int t = threadIdx.x;
    if (t < BATCH) {
        int idx = bmuidx[t];
        bi_s[t] = (float)loc[2 * idx];
        bj_s[t] = (float)loc[2 * idx + 1];
    }
    __syncthreads();

    const float lr    = lrp[0];
    const float alpha = 0.05f * lr;
    const float sig   = 50.0f * lr;
    const float inv   = 1.0f / (2.0f * sig * sig + 1e-5f);

    const int gl = t & 63;
    const int ch = t >> 6;
    const int g  = blockIdx.x * 64 + gl;
    const float gi = (float)(g / MCOLS);
    const float gj = (float)(g % MCOLS);

    float acc[DIM];
#pragma unroll
    for (int d = 0; d < DIM; ++d) acc[d] = 0.f;
    float s0 = 0.f;

    const int bbase = ch * 32;
    for (int i = 0; i < 32; ++i) {
        const int bu = __builtin_amdgcn_readfirstlane(bbase + i);  // wave-uniform
        const float dr = gi - bi_s[bu];
        const float dc = gj - bj_s[bu];
        const float w  = alpha * __expf(-fmaf(dr, dr, dc * dc) * inv);
        s0 += w;
        const float4* xr = (const float4*)(x + (size_t)bu * DIM);
#pragma unroll
        for (int k = 0; k < 8; ++k) {
            float4 xv = xr[k];
            acc[4*k+0] = fmaf(w, xv.x, acc[4*k+0]);
            acc[4*k+1] = fmaf(w, xv.y, acc[4*k+1]);
            acc[4*k+2] = fmaf(w, xv.z, acc[4*k+2]);
            acc[4*k+3] = fmaf(w, xv.w, acc[4*k+3]);
        }
    }

#pragma unroll
    for (int d = 0; d < DIM; ++d) red[ch][gl][d] = acc[d];
    red[ch][gl][32] = s0;
    __syncthreads();

    const int gl2  = t >> 2;
    const int part = t & 3;
    const int g2   = blockIdx.x * 64 + gl2;
    if (g2 < GRID_N) {
        const float ssum = red[0][gl2][32] + red[1][gl2][32] +
                           red[2][gl2][32] + red[3][gl2][32];
#pragma unroll
        for (int k = 0; k < 8; ++k) {
            const int d = part * 8 + k;
            const float a  = red[0][gl2][d] + red[1][gl2][d] +
                             red[2][gl2][d] + red[3][gl2][d];
            const float cg = c[(size_t)g2 * DIM + d];
            out[257 + (size_t)g2 * DIM + d] = cg + (a - ssum * cg) * (1.0f / 128.0f);
        }
    }
}

// ---------------------------------------------------------------------------
extern "C" void kernel_launch(void* const* d_in, const int* in_sizes, int n_in,
                              void* d_out, int out_size, void* d_ws, size_t ws_size,
                              hipStream_t stream) {
    const float* x   = (const float*)d_in[0];
    const float* c   = (const float*)d_in[1];
    const int*   loc = (const int*)d_in[2];
    // d_in[3] = distance_mat: recomputed on the fly (exact for integer coords)
    const float* lrp = (const float*)d_in[4];
    float* out = (float*)d_out;

    float* pmin   = (float*)d_ws;                         // 512 floats
    int*   pidx   = (int*)((char*)d_ws + 512 * 4);        // 512 ints
    int*   bmuidx = (int*)((char*)d_ws + 1024 * 4);       // 128 ints

    hipLaunchKernelGGL(k1_bmu,   dim3(256), dim3(256), 0, stream, x, c, pmin, pidx);
    hipLaunchKernelGGL(k2_final, dim3(1),   dim3(128), 0, stream, pmin, pidx, loc, out, bmuidx);
    hipLaunchKernelGGL(k3_update, dim3(157), dim3(256), 0, stream, x, c, loc, bmuidx, lrp, out);
}

// Round 2
// 23.123 us; speedup vs baseline: 1.1636x; 1.1636x over previous
//
#include <hip/hip_runtime.h>
#include <math.h>

#define BATCH 128
#define GRID_N 10000
#define DIM 32
#define MCOLS 100
#define NCHUNK 8      // g-chunks in K1
#define GCHUNK 1250   // g's per chunk

// ---------------------------------------------------------------------------
// K1: partial BMU search. 32 b-groups (4 rows of x each) x 8 g-chunks (1250)
// = 256 blocks, 256 threads. Direct-diff ||x-c||^2, first-index tie-break.
// Writes pmin/pidx[b*8+chunk].
// ---------------------------------------------------------------------------
__global__ __launch_bounds__(256) void k1_bmu(const float* __restrict__ x,
                                              const float* __restrict__ c,
                                              float* __restrict__ pmin,
                                              int* __restrict__ pidx) {
    const int blk   = blockIdx.x;
    const int bg    = blk >> 3;      // 0..31
    const int chunk = blk & 7;       // 0..7
    const int b0    = bg * 4;
    const int t     = threadIdx.x;

    float xr[4][DIM];
#pragma unroll
    for (int i = 0; i < 4; ++i)
#pragma unroll
        for (int d = 0; d < DIM; ++d)
            xr[i][d] = x[(b0 + i) * DIM + d];

    const int gstart = chunk * GCHUNK;
    const int gend   = gstart + GCHUNK;

    float best[4] = {3.4e38f, 3.4e38f, 3.4e38f, 3.4e38f};
    int   idx[4]  = {0, 0, 0, 0};

    for (int g = gstart + t; g < gend; g += 256) {
        const float4* cr = (const float4*)(c + (size_t)g * DIM);
        float d2[4] = {0.f, 0.f, 0.f, 0.f};
#pragma unroll
        for (int k = 0; k < 8; ++k) {
            float4 cv = cr[k];
#pragma unroll
            for (int i = 0; i < 4; ++i) {
                float a;
                a = xr[i][4*k+0] - cv.x; d2[i] = fmaf(a, a, d2[i]);
                a = xr[i][4*k+1] - cv.y; d2[i] = fmaf(a, a, d2[i]);
                a = xr[i][4*k+2] - cv.z; d2[i] = fmaf(a, a, d2[i]);
                a = xr[i][4*k+3] - cv.w; d2[i] = fmaf(a, a, d2[i]);
            }
        }
#pragma unroll
        for (int i = 0; i < 4; ++i)
            if (d2[i] < best[i]) { best[i] = d2[i]; idx[i] = g; }  // strict <: keeps first
    }

    // 64-lane butterfly, min with smallest-index tie-break
#pragma unroll
    for (int m = 1; m < 64; m <<= 1) {
#pragma unroll
        for (int i = 0; i < 4; ++i) {
            float o  = __shfl_xor(best[i], m);
            int   oi = __shfl_xor(idx[i], m);
            if (o < best[i] || (o == best[i] && oi < idx[i])) { best[i] = o; idx[i] = oi; }
        }
    }

    __shared__ float sm[4][4];
    __shared__ int   si[4][4];
    const int wave = t >> 6;
    const int lane = t & 63;
    if (lane == 0) {
#pragma unroll
        for (int i = 0; i < 4; ++i) { sm[i][wave] = best[i]; si[i][wave] = idx[i]; }
    }
    __syncthreads();
    if (t < 4) {
        float bb = sm[t][0]; int bi = si[t][0];
#pragma unroll
        for (int w = 1; w < 4; ++w)
            if (sm[t][w] < bb || (sm[t][w] == bb && si[t][w] < bi)) { bb = sm[t][w]; bi = si[t][w]; }
        pmin[(b0 + t) * NCHUNK + chunk] = bb;
        pidx[(b0 + t) * NCHUNK + chunk] = bi;
    }
}

// ---------------------------------------------------------------------------
// K3: finalize argmin (redundantly per block, 8 KB of L2-hot partials) +
// weight update. 157 blocks x 256 threads; thread = (g_local = t&63,
// b-chunk = t>>6 of 32 rows). Block 0 additionally writes bmu_loc and
// mean(mindist).
// ---------------------------------------------------------------------------
__global__ __launch_bounds__(256) void k3_update(const float* __restrict__ x,
                                                 const float* __restrict__ c,
                                                 const int* __restrict__ loc,
                                                 const float* __restrict__ pmin,
                                                 const int* __restrict__ pidx,
                                                 const float* __restrict__ lrp,
                                                 float* __restrict__ out) {
    __shared__ float bi_s[BATCH], bj_s[BATCH];
    __shared__ float red[4][64][33];
    __shared__ float partial[2];

    const int t = threadIdx.x;

    // ---- finalize per-b argmin over 8 chunks ----
    float msum = 0.f;
    if (t < BATCH) {
        float best = pmin[t * NCHUNK];
        int   bi   = pidx[t * NCHUNK];
#pragma unroll
        for (int k = 1; k < NCHUNK; ++k) {
            float v = pmin[t * NCHUNK + k];
            int   i = pidx[t * NCHUNK + k];
            if (v < best || (v == best && i < bi)) { best = v; bi = i; }
        }
        const float li = (float)loc[2 * bi];
        const float lj = (float)loc[2 * bi + 1];
        bi_s[t] = li;
        bj_s[t] = lj;
        if (blockIdx.x == 0) { out[2 * t] = li; out[2 * t + 1] = lj; }
        msum = sqrtf(fmaxf(best, 0.f));
    }
    // wave-sum of mindist (threads >=128 contribute 0)
#pragma unroll
    for (int m = 1; m < 64; m <<= 1) msum += __shfl_xor(msum, m);
    if (t < BATCH && (t & 63) == 0) partial[t >> 6] = msum;
    __syncthreads();
    if (blockIdx.x == 0 && t == 0) out[256] = (partial[0] + partial[1]) * (1.0f / 128.0f);

    // ---- weight update ----
    const float lr    = lrp[0];
    const float alpha = 0.05f * lr;
    const float sig   = 50.0f * lr;
    const float inv   = 1.0f / (2.0f * sig * sig + 1e-5f);

    const int gl = t & 63;
    const int ch = t >> 6;
    const int g  = blockIdx.x * 64 + gl;
    const float gi = (float)(g / MCOLS);
    const float gj = (float)(g % MCOLS);

    float acc[DIM];
#pragma unroll
    for (int d = 0; d < DIM; ++d) acc[d] = 0.f;
    float s0 = 0.f;

    const int bbase = ch * 32;
    for (int i = 0; i < 32; ++i) {
        const int bu = __builtin_amdgcn_readfirstlane(bbase + i);  // wave-uniform
        const float dr = gi - bi_s[bu];
        const float dc = gj - bj_s[bu];
        const float w  = alpha * __expf(-fmaf(dr, dr, dc * dc) * inv);
        s0 += w;
        const float4* xrp = (const float4*)(x + (size_t)bu * DIM);
#pragma unroll
        for (int k = 0; k < 8; ++k) {
            float4 xv = xrp[k];
            acc[4*k+0] = fmaf(w, xv.x, acc[4*k+0]);
            acc[4*k+1] = fmaf(w, xv.y, acc[4*k+1]);
            acc[4*k+2] = fmaf(w, xv.z, acc[4*k+2]);
            acc[4*k+3] = fmaf(w, xv.w, acc[4*k+3]);
        }
    }

#pragma unroll
    for (int d = 0; d < DIM; ++d) red[ch][gl][d] = acc[d];
    red[ch][gl][32] = s0;
    __syncthreads();

    const int gl2  = t >> 2;
    const int part = t & 3;
    const int g2   = blockIdx.x * 64 + gl2;
    if (g2 < GRID_N) {
        const float ssum = red[0][gl2][32] + red[1][gl2][32] +
                           red[2][gl2][32] + red[3][gl2][32];
#pragma unroll
        for (int k = 0; k < 8; ++k) {
            const int d = part * 8 + k;
            const float a  = red[0][gl2][d] + red[1][gl2][d] +
                             red[2][gl2][d] + red[3][gl2][d];
            const float cg = c[(size_t)g2 * DIM + d];
            out[257 + (size_t)g2 * DIM + d] = cg + (a - ssum * cg) * (1.0f / 128.0f);
        }
    }
}

// ---------------------------------------------------------------------------
extern "C" void kernel_launch(void* const* d_in, const int* in_sizes, int n_in,
                              void* d_out, int out_size, void* d_ws, size_t ws_size,
                              hipStream_t stream) {
    const float* x   = (const float*)d_in[0];
    const float* c   = (const float*)d_in[1];
    const int*   loc = (const int*)d_in[2];
    // d_in[3] = distance_mat: recomputed on the fly (exact for integer coords)
    const float* lrp = (const float*)d_in[4];
    float* out = (float*)d_out;

    float* pmin = (float*)d_ws;                        // 1024 floats
    int*   pidx = (int*)((char*)d_ws + 1024 * 4);      // 1024 ints

    hipLaunchKernelGGL(k1_bmu,    dim3(256), dim3(256), 0, stream, x, c, pmin, pidx);
    hipLaunchKernelGGL(k3_update, dim3(157), dim3(256), 0, stream, x, c, loc, pmin, pidx, lrp, out);
}